// Round 12
// baseline (39.169 us; speedup 1.0000x reference)
//
#include <hip/hip_runtime.h>
#include <hip/hip_bf16.h>

#define N_NODES   200000
#define N_PATCHES 256
#define TSTEPS    12
#define NHID      16
#define HORIZON   12
#define GDIM      192            // NHID * TSTEPS
#define IN_DIM    204            // GDIM + TSTEPS
#define PH_STRIDE 206            // padded row: 103 dwords (odd -> uniform banks)
#define PH_STRIDE_DW 103
#define NCHUNKS   6250           // N_NODES / 32 (exact)
#define THREADS   512
#define TOTAL_WAVES 2048         // 256 blocks x 8 waves

typedef __attribute__((ext_vector_type(8)))  short        bf16x8;
typedef __attribute__((ext_vector_type(16))) float        f32x16;
typedef __attribute__((ext_vector_type(4)))  unsigned int u32x4;

// pack two fp32 -> one dword of 2 bf16 (compiler fuses to v_cvt_pk_bf16_f32)
__device__ __forceinline__ unsigned int pk2(float lo, float hi) {
    unsigned short l = __builtin_bit_cast(unsigned short, __float2bfloat16(lo));
    unsigned short h = __builtin_bit_cast(unsigned short, __float2bfloat16(hi));
    return ((unsigned int)h << 16) | (unsigned int)l;
}

__device__ __forceinline__ bf16x8 frag_of(unsigned int a, unsigned int b,
                                          unsigned int c, unsigned int d) {
    u32x4 u; u[0] = a; u[1] = b; u[2] = c; u[3] = d;
    return __builtin_bit_cast(bf16x8, u);
}

__device__ __forceinline__ float bf16bits_lo(unsigned int w) {
    return __builtin_bit_cast(float, w << 16);
}
__device__ __forceinline__ float bf16bits_hi(unsigned int w) {
    return __builtin_bit_cast(float, w & 0xffff0000u);
}

// Clamped weight fetch helpers (OOB -> 0)
__device__ __forceinline__ float ldW1f(const float* __restrict__ W1, int k, int j) {
    const bool ok = (k < TSTEPS) && (j < IN_DIM);
    const int  idx = ok ? ((GDIM + k) * IN_DIM + j) : 0;
    const float v = W1[idx];
    return ok ? v : 0.0f;
}
__device__ __forceinline__ float ldW2t(const float* __restrict__ W2, int j, int o) {
    const bool ok = (j < IN_DIM) && (o < HORIZON);
    const int  idx = ok ? (j * HORIZON + o) : 0;
    const float v = W2[idx];
    return ok ? v : 0.0f;
}

// ---------------------------------------------------------------------------
// SINGLE fused kernel (grid 256 x 512, 125952 B LDS, 2 waves/SIMD).
// Phase A: each wave packs 2-3 weight fragments (stacked k-layout
//          m(e,hi)=(e&3)+8*(e>>2)+4*hi) into LDS wfl.
// Phase B: waves 0..6 compute the FULL patch table per block via MFMA GEMM
//          PH[p][j] = b1[j] + X(256x192) x W1(192x204), D written straight
//          into LDS (bf16, stride 206). Wave w owns j-tile w (32 cols),
//          loops 8 p-tiles x 12 k-tiles. Same A-row/B-col/k conventions
//          already validated by the node GEMMs.
// One barrier, then the R11 chunk loop (unchanged math): per-wave MFMA over
// chunks of 32 consecutive nodes, C-init from LDS PH, GEMM2 even/odd accs.
// No second dispatch, no global PH round-trip, no staging loop.
// ---------------------------------------------------------------------------
__global__ __launch_bounds__(THREADS) void fused_mlp(
    const float* __restrict__ mixer_x,        // (1,12,256,16)
    const float* __restrict__ features,       // (200000,12)
    const float* __restrict__ W1,             // (204,204)
    const float* __restrict__ b1,             // (204)
    const float* __restrict__ W2,             // (204,12)
    const float* __restrict__ b2,             // (12)
    const int*   __restrict__ node_patch,     // (200000)
    float* __restrict__ out)                  // (200000,12)
{
    __shared__ unsigned short ph[N_PATCHES * PH_STRIDE];  // 105472 B
    __shared__ u32x4 wfl[20 * 64];                        // 20480 B

    const int tid  = threadIdx.x;
    const int lane = tid & 63;
    const int wid  = tid >> 6;
    const int jl   = lane & 31;
    const int hi   = lane >> 5;
    const int kb   = 4 * hi;

    // ---- first chunk's loads: issue first, hide under phases A/B ----------
    int c = blockIdx.x * 8 + wid;                         // 0..2047
    float4 fa, fb, fc; int p;
    {
        const float4* fp0 = (const float4*)(features + (c * 32 + jl) * TSTEPS);
        fa = fp0[0]; fb = fp0[1]; fc = fp0[2];
        p  = node_patch[c * 32 + jl];
    }
    const float4 b2A = *(const float4*)(b2 + 4 * hi);     // b2[0..3] / b2[4..7]
    const float4 b2B = *(const float4*)(b2 + 8);          // b2[8..11] (hi0)

    // ---- Phase A: weight fragments -> LDS (all 8 waves) -------------------
    for (int f = wid; f < 20; f += 8) {
        u32x4 u;
        if (f < 7) {
            const int j = f * 32 + jl;
            u[0] = pk2(ldW1f(W1, kb + 0,  j), ldW1f(W1, kb + 1,  j));
            u[1] = pk2(ldW1f(W1, kb + 2,  j), ldW1f(W1, kb + 3,  j));
            u[2] = pk2(ldW1f(W1, kb + 8,  j), ldW1f(W1, kb + 9,  j));
            u[3] = pk2(ldW1f(W1, kb + 10, j), ldW1f(W1, kb + 11, j));
        } else {
            const int j0 = (f - 7) * 16 + kb;
            u[0] = pk2(ldW2t(W2, j0 + 0,  jl), ldW2t(W2, j0 + 1,  jl));
            u[1] = pk2(ldW2t(W2, j0 + 2,  jl), ldW2t(W2, j0 + 3,  jl));
            u[2] = pk2(ldW2t(W2, j0 + 8,  jl), ldW2t(W2, j0 + 9,  jl));
            u[3] = pk2(ldW2t(W2, j0 + 10, jl), ldW2t(W2, j0 + 11, jl));
        }
        wfl[f * 64 + lane] = u;
    }

    // ---- Phase B: PH GEMM into LDS (waves 0..6; wave w = j-tile w) --------
    if (wid < 7) {
        const int j0 = wid * 32;
        const int jc = (j0 + jl < IN_DIM) ? (j0 + jl) : (IN_DIM - 1);

        // B-frags: W1[k][jc], k = kt*16 + m(e,hi)
        bf16x8 Bf[12];
#pragma unroll
        for (int kt = 0; kt < 12; ++kt) {
            const int r = kt * 16 + kb;
            Bf[kt] = frag_of(
                pk2(W1[(r + 0)  * IN_DIM + jc], W1[(r + 1)  * IN_DIM + jc]),
                pk2(W1[(r + 2)  * IN_DIM + jc], W1[(r + 3)  * IN_DIM + jc]),
                pk2(W1[(r + 8)  * IN_DIM + jc], W1[(r + 9)  * IN_DIM + jc]),
                pk2(W1[(r + 10) * IN_DIM + jc], W1[(r + 11) * IN_DIM + jc]));
        }
        const float bini = b1[jc];
        const bool  jok  = (j0 + jl < IN_DIM);

        for (int pt = 0; pt < 8; ++pt) {
            // A-frags: X[p][k], p = pt*32+jl, X[p][t*16+f] = mixer_x[(t*256+p)*16+f]
            const float* xb = mixer_x + (pt * 32 + jl) * NHID;

            f32x16 acc;
#pragma unroll
            for (int e = 0; e < 16; ++e) acc[e] = bini;

#pragma unroll
            for (int kt = 0; kt < 12; ++kt) {
                const float* xk = xb + kt * (N_PATCHES * NHID);
                const float4 xa = *(const float4*)(xk + kb);
                const float4 xc = *(const float4*)(xk + 8 + kb);
                const bf16x8 Af = frag_of(pk2(xa.x, xa.y), pk2(xa.z, xa.w),
                                          pk2(xc.x, xc.y), pk2(xc.z, xc.w));
                acc = __builtin_amdgcn_mfma_f32_32x32x16_bf16(Af, Bf[kt], acc, 0, 0, 0);
            }

            if (jok) {
#pragma unroll
                for (int e = 0; e < 16; ++e) {
                    const int prow = pt * 32 + (e & 3) + 8 * (e >> 2) + 4 * hi;
                    ph[prow * PH_STRIDE + j0 + jl] =
                        __builtin_bit_cast(unsigned short, __float2bfloat16(acc[e]));
                }
            }
        }
    }

    __syncthreads();

    // ---- load node-GEMM weight fragments from LDS -------------------------
    bf16x8 A1f[7], A2f[13];
#pragma unroll
    for (int f = 0; f < 7; ++f)
        A1f[f] = __builtin_bit_cast(bf16x8, wfl[f * 64 + lane]);
#pragma unroll
    for (int f = 0; f < 13; ++f)
        A2f[f] = __builtin_bit_cast(bf16x8, wfl[(7 + f) * 64 + lane]);

    // ---- chunk loop (identical math to R11) -------------------------------
    while (true) {
        const int  cn    = c + TOTAL_WAVES;
        const bool haveN = (cn < NCHUNKS);
        float4 fa2, fb2, fc2; int p2 = 0;
        if (haveN) {                                      // prefetch next chunk
            const float4* fq = (const float4*)(features + (cn * 32 + jl) * TSTEPS);
            fa2 = fq[0]; fb2 = fq[1]; fc2 = fq[2];
            p2  = node_patch[cn * 32 + jl];
        }

        // B1: F^T[k][node], stacked layout (k>=12 -> 0)
        const bf16x8 B1 = frag_of(hi ? pk2(fb.x, fb.y) : pk2(fa.x, fa.y),
                                  hi ? pk2(fb.z, fb.w) : pk2(fa.z, fa.w),
                                  hi ? 0u              : pk2(fc.x, fc.y),
                                  hi ? 0u              : pk2(fc.z, fc.w));

        const unsigned int* dwrow = (const unsigned int*)ph + p * PH_STRIDE_DW;

        f32x16 oE, oO;
#pragma unroll
        for (int e = 0; e < 16; ++e) { oE[e] = 0.0f; oO[e] = 0.0f; }

        // tile-0 C-init loads (b32 pairs, uniform banks)
        unsigned int nx[8];
#pragma unroll
        for (int G = 0; G < 4; ++G) {
            const int di = 4 * G + 2 * hi;
            nx[2 * G]     = dwrow[di];
            nx[2 * G + 1] = dwrow[di + 1];
        }

#pragma unroll
        for (int t = 0; t < 7; ++t) {
            unsigned int cu[8];
#pragma unroll
            for (int g = 0; g < 8; ++g) cu[g] = nx[g];

            if (t < 6) {                                  // prefetch tile t+1
#pragma unroll
                for (int G = 0; G < 4; ++G) {
                    const int e  = (t + 1) * 32 + 8 * G + 4 * hi;
                    const bool ok = (e <= 200);
                    const int di = ok ? (e >> 1) : 0;
                    nx[2 * G]     = dwrow[di];
                    nx[2 * G + 1] = dwrow[di + 1];
                }
            }

            f32x16 acc;
#pragma unroll
            for (int G = 0; G < 4; ++G) {
                const bool ok = (t * 32 + 8 * G + 4 * hi) <= 200;
                acc[4 * G + 0] = ok ? bf16bits_lo(cu[2 * G])     : 0.0f;
                acc[4 * G + 1] = ok ? bf16bits_hi(cu[2 * G])     : 0.0f;
                acc[4 * G + 2] = ok ? bf16bits_lo(cu[2 * G + 1]) : 0.0f;
                acc[4 * G + 3] = ok ? bf16bits_hi(cu[2 * G + 1]) : 0.0f;
            }

            acc = __builtin_amdgcn_mfma_f32_32x32x16_bf16(A1f[t], B1, acc, 0, 0, 0);

            const bf16x8 ba = frag_of(
                pk2(fmaxf(acc[0], 0.f), fmaxf(acc[1], 0.f)),
                pk2(fmaxf(acc[2], 0.f), fmaxf(acc[3], 0.f)),
                pk2(fmaxf(acc[4], 0.f), fmaxf(acc[5], 0.f)),
                pk2(fmaxf(acc[6], 0.f), fmaxf(acc[7], 0.f)));
            oE = __builtin_amdgcn_mfma_f32_32x32x16_bf16(A2f[2 * t], ba, oE, 0, 0, 0);

            if (t < 6) {
                const bf16x8 bb = frag_of(
                    pk2(fmaxf(acc[8],  0.f), fmaxf(acc[9],  0.f)),
                    pk2(fmaxf(acc[10], 0.f), fmaxf(acc[11], 0.f)),
                    pk2(fmaxf(acc[12], 0.f), fmaxf(acc[13], 0.f)),
                    pk2(fmaxf(acc[14], 0.f), fmaxf(acc[15], 0.f)));
                oO = __builtin_amdgcn_mfma_f32_32x32x16_bf16(A2f[2 * t + 1], bb, oO, 0, 0, 0);
            }
        }

        // ---- store: D row of elem e = (e&3)+8*(e>>2)+4*hi, col = node -----
        {
            const int node = c * 32 + jl;                 // always < N_NODES
            float* orow = out + node * HORIZON;
            const float s0 = oE[0] + oO[0], s1 = oE[1] + oO[1];
            const float s2 = oE[2] + oO[2], s3 = oE[3] + oO[3];
            if (hi == 0) {
                const float s4 = oE[4] + oO[4], s5 = oE[5] + oO[5];
                const float s6 = oE[6] + oO[6], s7 = oE[7] + oO[7];
                *(float4*)(orow + 0) = make_float4(s0 + b2A.x, s1 + b2A.y,
                                                   s2 + b2A.z, s3 + b2A.w);
                *(float4*)(orow + 8) = make_float4(s4 + b2B.x, s5 + b2B.y,
                                                   s6 + b2B.z, s7 + b2B.w);
            } else {
                *(float4*)(orow + 4) = make_float4(s0 + b2A.x, s1 + b2A.y,
                                                   s2 + b2A.z, s3 + b2A.w);
            }
        }

        if (!haveN) break;
        fa = fa2; fb = fb2; fc = fc2; p = p2; c = cn;
    }
}

// ---------------------------------------------------------------------------
extern "C" void kernel_launch(void* const* d_in, const int* in_sizes, int n_in,
                              void* d_out, int out_size, void* d_ws, size_t ws_size,
                              hipStream_t stream) {
    const float* mixer_x    = (const float*)d_in[0];
    const float* features   = (const float*)d_in[1];
    const float* W1         = (const float*)d_in[2];
    const float* b1         = (const float*)d_in[3];
    const float* W2         = (const float*)d_in[4];
    const float* b2         = (const float*)d_in[5];
    const int*   node_patch = (const int*)d_in[6];
    float* out = (float*)d_out;

    fused_mlp<<<256, THREADS, 0, stream>>>(mixer_x, features, W1, b1, W2, b2,
                                           node_patch, out);
}

// Round 14
// 26.139 us; speedup vs baseline: 1.4985x; 1.4985x over previous
//
#include <hip/hip_runtime.h>
#include <hip/hip_bf16.h>

#define N_NODES   200000
#define N_PATCHES 256
#define TSTEPS    12
#define NHID      16
#define HORIZON   12
#define GDIM      192            // NHID * TSTEPS
#define IN_DIM    204            // GDIM + TSTEPS
#define PH_STRIDE 206            // padded row: 103 dwords (odd -> uniform banks)
#define PH_STRIDE_DW 103
#define NPAIRS    3125           // 200000 / 64 (exact)
#define K2_THREADS 512
#define TOTAL_WAVES 2048         // 256 blocks x 8 waves
#define TBL_U4    6592           // 256*206*2 bytes / 16

typedef __attribute__((ext_vector_type(8)))  short        bf16x8;
typedef __attribute__((ext_vector_type(16))) float        f32x16;
typedef __attribute__((ext_vector_type(4)))  unsigned int u32x4;

// pack two fp32 -> one dword of 2 bf16 (compiler fuses to v_cvt_pk_bf16_f32)
__device__ __forceinline__ unsigned int pk2(float lo, float hi) {
    unsigned short l = __builtin_bit_cast(unsigned short, __float2bfloat16(lo));
    unsigned short h = __builtin_bit_cast(unsigned short, __float2bfloat16(hi));
    return ((unsigned int)h << 16) | (unsigned int)l;
}

__device__ __forceinline__ bf16x8 frag_of(unsigned int a, unsigned int b,
                                          unsigned int c, unsigned int d) {
    u32x4 u; u[0] = a; u[1] = b; u[2] = c; u[3] = d;
    return __builtin_bit_cast(bf16x8, u);
}

__device__ __forceinline__ float bf16bits_lo(unsigned int w) {
    return __builtin_bit_cast(float, w << 16);
}
__device__ __forceinline__ float bf16bits_hi(unsigned int w) {
    return __builtin_bit_cast(float, w & 0xffff0000u);
}

// async global->LDS copy, 16B per lane (wave-uniform base + lane*16 dest)
__device__ __forceinline__ void gload_lds16(const uint4* g, uint4* l) {
    __builtin_amdgcn_global_load_lds(
        (const __attribute__((address_space(1))) unsigned int*)g,
        (__attribute__((address_space(3))) unsigned int*)l,
        16, 0, 0);
}

// Clamped weight fetch helpers (OOB -> 0)
__device__ __forceinline__ float ldW1f(const float* __restrict__ W1, int k, int j) {
    const bool ok = (k < TSTEPS) && (j < IN_DIM);
    const int  idx = ok ? ((GDIM + k) * IN_DIM + j) : 0;
    const float v = W1[idx];
    return ok ? v : 0.0f;
}
__device__ __forceinline__ float ldW2t(const float* __restrict__ W2, int j, int o) {
    const bool ok = (j < IN_DIM) && (o < HORIZON);
    const int  idx = ok ? (j * HORIZON + o) : 0;
    const float v = W2[idx];
    return ok ? v : 0.0f;
}

// guarded C-init expansion from LDS (identical semantics to R11)
__device__ __forceinline__ void cinit_tile(const unsigned int* __restrict__ dwrow,
                                           int t, int hi, f32x16& acc) {
#pragma unroll
    for (int G = 0; G < 4; ++G) {
        const int e  = t * 32 + 8 * G + 4 * hi;
        const bool ok = (e <= 200);                  // e+3 <= 203
        const int di = ok ? (e >> 1) : 0;
        const unsigned int r0 = dwrow[di];
        const unsigned int r1 = dwrow[di + 1];
        acc[4 * G + 0] = ok ? bf16bits_lo(r0) : 0.0f;
        acc[4 * G + 1] = ok ? bf16bits_hi(r0) : 0.0f;
        acc[4 * G + 2] = ok ? bf16bits_lo(r1) : 0.0f;
        acc[4 * G + 3] = ok ? bf16bits_hi(r1) : 0.0f;
    }
}

// ---------------------------------------------------------------------------
// Kernel 1 (grid 257 x 1024) — EXACT R11 version (proven):
//  blocks 0..255 : patch_hb[p][j] = bf16(b1[j] + sum_{i<192} x[p][i]*W1[i][j])
//  block 256     : pack per-lane MFMA weight fragments (stacked k-layout
//                  m(e,hi) = (e&3)+8*(e>>2)+4*hi) into wfrag.
// ---------------------------------------------------------------------------
__global__ __launch_bounds__(1024) void precompute(
    const float* __restrict__ mixer_x,   // (1,12,256,16)
    const float* __restrict__ W1,        // (204,204)
    const float* __restrict__ b1,        // (204)
    const float* __restrict__ W2,        // (204,12)
    unsigned short* __restrict__ patch_hb, // (256,206) bf16
    u32x4* __restrict__ wfrag)           // (20,64)
{
    const int blk = blockIdx.x;
    const int tid = threadIdx.x;

    if (blk == N_PATCHES) {
        const int lane = tid & 63;
        const int g    = tid >> 6;        // 0..15
        const int jl   = lane & 31;
        const int kb   = 4 * (lane >> 5);
        for (int f = g; f < 20; f += 16) {
            u32x4 u;
            if (f < 7) {
                const int j = f * 32 + jl;
                u[0] = pk2(ldW1f(W1, kb + 0,  j), ldW1f(W1, kb + 1,  j));
                u[1] = pk2(ldW1f(W1, kb + 2,  j), ldW1f(W1, kb + 3,  j));
                u[2] = pk2(ldW1f(W1, kb + 8,  j), ldW1f(W1, kb + 9,  j));
                u[3] = pk2(ldW1f(W1, kb + 10, j), ldW1f(W1, kb + 11, j));
            } else {
                const int j0 = (f - 7) * 16 + kb;
                u[0] = pk2(ldW2t(W2, j0 + 0,  jl), ldW2t(W2, j0 + 1,  jl));
                u[1] = pk2(ldW2t(W2, j0 + 2,  jl), ldW2t(W2, j0 + 3,  jl));
                u[2] = pk2(ldW2t(W2, j0 + 8,  jl), ldW2t(W2, j0 + 9,  jl));
                u[3] = pk2(ldW2t(W2, j0 + 10, jl), ldW2t(W2, j0 + 11, jl));
            }
            wfrag[f * 64 + lane] = u;
        }
        return;
    }

    __shared__ float xs[GDIM];
    __shared__ float partial[3 * IN_DIM];
    const int p = blk;
    const int j = tid & 255;
    const int q = tid >> 8;               // i-quarter 0..3

    if (tid < GDIM) {
        const int t = tid >> 4, f = tid & 15;
        xs[tid] = mixer_x[(t * N_PATCHES + p) * NHID + f];
    }
    __syncthreads();

    float acc = 0.0f;
    if (j < IN_DIM) {
        acc = (q == 0) ? b1[j] : 0.0f;
        const int ibase = q * 48;
#pragma unroll 16
        for (int i = 0; i < 48; ++i)
            acc = fmaf(xs[ibase + i], W1[(ibase + i) * IN_DIM + j], acc);
        if (q > 0) partial[(q - 1) * IN_DIM + j] = acc;
    }
    __syncthreads();
    if (q == 0 && j < IN_DIM) {
        const float v = acc + partial[j] + partial[IN_DIM + j] + partial[2 * IN_DIM + j];
        patch_hb[p * PH_STRIDE + j] =
            __builtin_bit_cast(unsigned short, __float2bfloat16(v));
    }
}

// ---------------------------------------------------------------------------
// Kernel 2 (grid 256 x 512, 105472 B LDS): async-stage bf16 patch table
// (stride 206 = 103 dw, uniform banks), then PAIR-ILP chunk loop: each wave
// owns a PAIR of adjacent 32-node chunks (pair pr -> nodes 64*pr..64*pr+63,
// pr = blk*8+wid, stride 2048, 3125 pairs exact). The two chunks' ds_reads
// and MFMA chains are independent -> 2x ILP against chain latency, same
// occupancy, same math as R11 (guarded b32 C-init, even/odd accumulators).
// ---------------------------------------------------------------------------
__global__ __launch_bounds__(K2_THREADS) void node_mlp_mfma(
    const float* __restrict__ features,       // (200000,12)
    const int*   __restrict__ node_patch,     // (200000)
    const unsigned short* __restrict__ patch_hb, // (256,206) bf16
    const u32x4* __restrict__ wfrag,          // (20,64)
    const float* __restrict__ b2,             // (12)
    float* __restrict__ out)                  // (200000,12)
{
    __shared__ unsigned short smem[N_PATCHES * PH_STRIDE];   // 105472 B

    const int tid  = threadIdx.x;
    const int lane = tid & 63;
    const int wid  = tid >> 6;
    const int jl   = lane & 31;
    const int hi   = lane >> 5;

    // ---- first pair's loads: issue before staging -------------------------
    int pr = blockIdx.x * 8 + wid;                        // 0..2047
    float4 faA, fbA, fcA, faB, fbB, fcB; int pA, pB;
    {
        const int nA = pr * 64 + jl;
        const int nB = nA + 32;
        const float4* fpA = (const float4*)(features + nA * TSTEPS);
        const float4* fpB = (const float4*)(features + nB * TSTEPS);
        faA = fpA[0]; fbA = fpA[1]; fcA = fpA[2];
        faB = fpB[0]; fbB = fpB[1]; fcB = fpB[2];
        pA  = node_patch[nA];
        pB  = node_patch[nB];
    }

    bf16x8 A1f[7], A2f[13];
#pragma unroll
    for (int f = 0; f < 7; ++f)
        A1f[f] = __builtin_bit_cast(bf16x8, wfrag[f * 64 + lane]);
#pragma unroll
    for (int f = 0; f < 13; ++f)
        A2f[f] = __builtin_bit_cast(bf16x8, wfrag[(7 + f) * 64 + lane]);

    const float4 b2A = *(const float4*)(b2 + 4 * hi);     // b2[0..3] / b2[4..7]
    const float4 b2B = *(const float4*)(b2 + 8);          // b2[8..11] (hi0)

    // ---- async stage bf16 patch table -> LDS ------------------------------
    {
        const uint4* src = (const uint4*)patch_hb;
        uint4* dst = (uint4*)smem;
#pragma unroll
        for (int k = 0; k < 13; ++k) {
            const int i = tid + k * K2_THREADS;
            if (i < TBL_U4) gload_lds16(src + i, dst + i);
        }
    }
    __syncthreads();   // drains vmcnt (incl. global_load_lds) + lgkm

    // ---- pair loop ---------------------------------------------------------
    while (true) {
        // B1 operands: F^T[k][node], stacked layout (k>=12 -> 0)
        const bf16x8 B1A = frag_of(hi ? pk2(fbA.x, fbA.y) : pk2(faA.x, faA.y),
                                   hi ? pk2(fbA.z, fbA.w) : pk2(faA.z, faA.w),
                                   hi ? 0u                : pk2(fcA.x, fcA.y),
                                   hi ? 0u                : pk2(fcA.z, fcA.w));
        const bf16x8 B1B = frag_of(hi ? pk2(fbB.x, fbB.y) : pk2(faB.x, faB.y),
                                   hi ? pk2(fbB.z, fbB.w) : pk2(faB.z, faB.w),
                                   hi ? 0u                : pk2(fcB.x, fcB.y),
                                   hi ? 0u                : pk2(fcB.z, fcB.w));

        const unsigned int* rowA = (const unsigned int*)smem + pA * PH_STRIDE_DW;
        const unsigned int* rowB = (const unsigned int*)smem + pB * PH_STRIDE_DW;

        f32x16 oEA, oOA, oEB, oOB;
#pragma unroll
        for (int e = 0; e < 16; ++e) {
            oEA[e] = 0.0f; oOA[e] = 0.0f; oEB[e] = 0.0f; oOB[e] = 0.0f;
        }

#pragma unroll
        for (int t = 0; t < 7; ++t) {
            f32x16 accA, accB;
            cinit_tile(rowA, t, hi, accA);     // 8 independent ds_reads (A)
            cinit_tile(rowB, t, hi, accB);     // 8 independent ds_reads (B)

            accA = __builtin_amdgcn_mfma_f32_32x32x16_bf16(A1f[t], B1A, accA, 0, 0, 0);
            accB = __builtin_amdgcn_mfma_f32_32x32x16_bf16(A1f[t], B1B, accB, 0, 0, 0);

            const bf16x8 baA = frag_of(
                pk2(fmaxf(accA[0], 0.f), fmaxf(accA[1], 0.f)),
                pk2(fmaxf(accA[2], 0.f), fmaxf(accA[3], 0.f)),
                pk2(fmaxf(accA[4], 0.f), fmaxf(accA[5], 0.f)),
                pk2(fmaxf(accA[6], 0.f), fmaxf(accA[7], 0.f)));
            const bf16x8 baB = frag_of(
                pk2(fmaxf(accB[0], 0.f), fmaxf(accB[1], 0.f)),
                pk2(fmaxf(accB[2], 0.f), fmaxf(accB[3], 0.f)),
                pk2(fmaxf(accB[4], 0.f), fmaxf(accB[5], 0.f)),
                pk2(fmaxf(accB[6], 0.f), fmaxf(accB[7], 0.f)));
            oEA = __builtin_amdgcn_mfma_f32_32x32x16_bf16(A2f[2 * t], baA, oEA, 0, 0, 0);
            oEB = __builtin_amdgcn_mfma_f32_32x32x16_bf16(A2f[2 * t], baB, oEB, 0, 0, 0);

            if (t < 6) {
                const bf16x8 bbA = frag_of(
                    pk2(fmaxf(accA[8],  0.f), fmaxf(accA[9],  0.f)),
                    pk2(fmaxf(accA[10], 0.f), fmaxf(accA[11], 0.f)),
                    pk2(fmaxf(accA[12], 0.f), fmaxf(accA[13], 0.f)),
                    pk2(fmaxf(accA[14], 0.f), fmaxf(accA[15], 0.f)));
                const bf16x8 bbB = frag_of(
                    pk2(fmaxf(accB[8],  0.f), fmaxf(accB[9],  0.f)),
                    pk2(fmaxf(accB[10], 0.f), fmaxf(accB[11], 0.f)),
                    pk2(fmaxf(accB[12], 0.f), fmaxf(accB[13], 0.f)),
                    pk2(fmaxf(accB[14], 0.f), fmaxf(accB[15], 0.f)));
                oOA = __builtin_amdgcn_mfma_f32_32x32x16_bf16(A2f[2 * t + 1], bbA, oOA, 0, 0, 0);
                oOB = __builtin_amdgcn_mfma_f32_32x32x16_bf16(A2f[2 * t + 1], bbB, oOB, 0, 0, 0);
            }
        }

        // ---- stores: D row of elem e = (e&3)+8*(e>>2)+4*hi, col = node ----
        {
            const int nA = pr * 64 + jl;
            float* orow = out + nA * HORIZON;
            const float s0 = oEA[0] + oOA[0], s1 = oEA[1] + oOA[1];
            const float s2 = oEA[2] + oOA[2], s3 = oEA[3] + oOA[3];
            if (hi == 0) {
                const float s4 = oEA[4] + oOA[4], s5 = oEA[5] + oOA[5];
                const float s6 = oEA[6] + oOA[6], s7 = oEA[7] + oOA[7];
                *(float4*)(orow + 0) = make_float4(s0 + b2A.x, s1 + b2A.y,
                                                   s2 + b2A.z, s3 + b2A.w);
                *(float4*)(orow + 8) = make_float4(s4 + b2B.x, s5 + b2B.y,
                                                   s6 + b2B.z, s7 + b2B.w);
            } else {
                *(float4*)(orow + 4) = make_float4(s0 + b2A.x, s1 + b2A.y,
                                                   s2 + b2A.z, s3 + b2A.w);
            }
        }
        {
            const int nB = pr * 64 + 32 + jl;
            float* orow = out + nB * HORIZON;
            const float s0 = oEB[0] + oOB[0], s1 = oEB[1] + oOB[1];
            const float s2 = oEB[2] + oOB[2], s3 = oEB[3] + oOB[3];
            if (hi == 0) {
                const float s4 = oEB[4] + oOB[4], s5 = oEB[5] + oOB[5];
                const float s6 = oEB[6] + oOB[6], s7 = oEB[7] + oOB[7];
                *(float4*)(orow + 0) = make_float4(s0 + b2A.x, s1 + b2A.y,
                                                   s2 + b2A.z, s3 + b2A.w);
                *(float4*)(orow + 8) = make_float4(s4 + b2B.x, s5 + b2B.y,
                                                   s6 + b2B.z, s7 + b2B.w);
            } else {
                *(float4*)(orow + 4) = make_float4(s0 + b2A.x, s1 + b2A.y,
                                                   s2 + b2A.z, s3 + b2A.w);
            }
        }

        pr += TOTAL_WAVES;
        if (pr >= NPAIRS) break;

        // next pair's loads
        const int nA = pr * 64 + jl;
        const int nB = nA + 32;
        const float4* fpA = (const float4*)(features + nA * TSTEPS);
        const float4* fpB = (const float4*)(features + nB * TSTEPS);
        faA = fpA[0]; fbA = fpA[1]; fcA = fpA[2];
        faB = fpB[0]; fbB = fpB[1]; fcB = fpB[2];
        pA  = node_patch[nA];
        pB  = node_patch[nB];
    }
}

// ---------------------------------------------------------------------------
extern "C" void kernel_launch(void* const* d_in, const int* in_sizes, int n_in,
                              void* d_out, int out_size, void* d_ws, size_t ws_size,
                              hipStream_t stream) {
    const float* mixer_x    = (const float*)d_in[0];
    const float* features   = (const float*)d_in[1];
    const float* W1         = (const float*)d_in[2];
    const float* b1         = (const float*)d_in[3];
    const float* W2         = (const float*)d_in[4];
    const float* b2         = (const float*)d_in[5];
    const int*   node_patch = (const int*)d_in[6];
    float* out = (float*)d_out;

    unsigned short* patch_hb = (unsigned short*)d_ws;          // 105472 B
    u32x4*          wfrag    = (u32x4*)((char*)d_ws + 105472); // +20480 B

    precompute<<<257, 1024, 0, stream>>>(mixer_x, W1, b1, W2, patch_hb, wfrag);

    node_mlp_mfma<<<256, K2_THREADS, 0, stream>>>(features, node_patch,
                                                  patch_hb, wfrag, b2, out);
}